// Round 15
// baseline (157.530 us; speedup 1.0000x reference)
//
#include <hip/hip_runtime.h>
#include <cstdint>
#include <cstddef>

typedef _Float16 half4_t  __attribute__((ext_vector_type(4)));
typedef _Float16 half8_t  __attribute__((ext_vector_type(8)));
typedef short    short4_t __attribute__((ext_vector_type(4)));
typedef unsigned short ushort4_t __attribute__((ext_vector_type(4)));
typedef float    f32x4_t  __attribute__((ext_vector_type(4)));

#define LOG2E 1.44269504088896340736f

__device__ __forceinline__ float bf2f(unsigned short u) {
    union { unsigned int u; float f; } x;
    x.u = ((unsigned int)u) << 16;
    return x.f;
}
__device__ __forceinline__ unsigned short f2bf(float f) {  // RNE
    union { float f; unsigned int u; } x;
    x.f = f;
    unsigned int r = (x.u + 0x7FFFu + ((x.u >> 16) & 1u)) >> 16;
    return (unsigned short)r;
}
__device__ __forceinline__ unsigned short f2bf_trunc(float f) {  // truncate (positive)
    union { float f; unsigned int u; } x;
    x.f = f;
    return (unsigned short)(x.u >> 16);
}

// ---------------------------------------------------------------------------
// Kernel A: prep + xt fused (unchanged from R12).
// ---------------------------------------------------------------------------
__global__ __launch_bounds__(256) void prep_kernel(
    const void* __restrict__ x,
    const void* __restrict__ qw, const void* __restrict__ kw, const void* __restrict__ vw,
    const void* __restrict__ qb, const void* __restrict__ kb, const void* __restrict__ vb,
    int* __restrict__ flag,
    _Float16* __restrict__ w2, float* __restrict__ bb, _Float16* __restrict__ xT)
{
    __shared__ int scnt;
    __shared__ _Float16 tile[64][66];

    if (threadIdx.x == 0) scnt = 0;
    __syncthreads();
    {
        unsigned int w = ((const unsigned int*)x)[threadIdx.x];
        int e = (w >> 7) & 0xFF;
        int hit = (e == 0) || (e >= 0x68 && e <= 0x88);
        atomicAdd(&scnt, hit);
    }
    __syncthreads();
    const int bf = (scnt >= 128) ? 1 : 0;
    if (blockIdx.x == 0 && threadIdx.x == 0) flag[0] = bf;

    if (blockIdx.x < 144) {
        int idx = blockIdx.x * 256 + threadIdx.x;
        if (idx < 36864) {
            int conv = idx / 12288;
            int r    = idx - conv * 12288;
            int tap  = r >> 12;
            int r2   = r & 4095;
            int co   = r2 >> 6;
            int ci   = r2 & 63;
            const void* w = (conv == 0) ? qw : (conv == 1) ? kw : vw;
            float t;
            if (bf) t = bf2f(((const unsigned short*)w)[co * 192 + ci * 3 + tap]);
            else    t = ((const float*)w)[co * 192 + ci * 3 + tap];
            if (conv == 0) t *= LOG2E;
            w2[idx] = (_Float16)t;
        }
        if (idx < 192) {
            int a = idx >> 6, co = idx & 63;
            const void* s = (a == 0) ? qb : (a == 1) ? kb : vb;
            float t = bf ? bf2f(((const unsigned short*)s)[co]) : ((const float*)s)[co];
            if (a == 0) t *= LOG2E;
            bb[idx] = t;
        }
    } else {
        const int bx   = blockIdx.x - 144;   // 0..249
        const int b    = bx / 125;
        const int n0   = (bx - b * 125) * 64;
        const int lane = threadIdx.x & 63;
        const int wv   = threadIdx.x >> 6;

        if (bf) {
            const unsigned short* xb = (const unsigned short*)x + (size_t)b * 512000 + n0 + lane;
#pragma unroll
            for (int i = 0; i < 16; ++i) {
                const int ci = wv * 16 + i;
                tile[ci][lane] = (_Float16)bf2f(xb[(size_t)ci * 8000]);
            }
        } else {
            const float* xb = (const float*)x + (size_t)b * 512000 + n0 + lane;
#pragma unroll
            for (int i = 0; i < 16; ++i) {
                const int ci = wv * 16 + i;
                tile[ci][lane] = (_Float16)xb[(size_t)ci * 8000];
            }
        }
        __syncthreads();
        _Float16* out = xT + ((size_t)b * 8000 + n0) * 64 + lane;
#pragma unroll
        for (int i = 0; i < 16; ++i) {
            const int r = wv * 16 + i;
            out[(size_t)r * 64] = tile[lane][r];
        }
    }
}

// ---------------------------------------------------------------------------
// Kernel B: the three convs as MFMA GEMMs (unchanged from R10/R12).
// ---------------------------------------------------------------------------
__global__ __launch_bounds__(256, 2) void convg_kernel(
    const _Float16* __restrict__ xT, const _Float16* __restrict__ w2,
    const float* __restrict__ bb,
    _Float16* __restrict__ Qt, _Float16* __restrict__ Kt, unsigned short* __restrict__ Vt)
{
    const int tid = threadIdx.x;
    const int wv  = tid >> 6;
    const int L   = tid & 63;
    const int q4  = L >> 4;
    const int lm  = L & 15;
    const int W    = blockIdx.x * 4 + wv;
    const int conv = W % 3;
    const int u    = W / 3;
    const int b    = u / 250;
    const int n0   = (u - b * 250) * 32;

    half8_t wf[3][2][4];
    const _Float16* wbase = w2 + (size_t)conv * 12288;
#pragma unroll
    for (int tap = 0; tap < 3; ++tap)
#pragma unroll
        for (int kh = 0; kh < 2; ++kh)
#pragma unroll
            for (int cb = 0; cb < 4; ++cb)
                wf[tap][kh][cb] = *(const half8_t*)(
                    wbase + ((size_t)(tap * 64 + cb * 16 + lm)) * 64 + kh * 32 + q4 * 8);

    f32x4_t acc[2][4];
#pragma unroll
    for (int cb = 0; cb < 4; ++cb) {
        const float bi = bb[conv * 64 + cb * 16 + lm];
        const f32x4_t v = (f32x4_t){bi, bi, bi, bi};
        acc[0][cb] = v;
        acc[1][cb] = v;
    }

    const _Float16* xb = xT + (size_t)b * 512000;
    const half8_t z8 = {(_Float16)0, (_Float16)0, (_Float16)0, (_Float16)0,
                        (_Float16)0, (_Float16)0, (_Float16)0, (_Float16)0};

#pragma unroll
    for (int mt = 0; mt < 2; ++mt) {
        const int npos = n0 + mt * 16 + lm;
        int gm, gp, off;
        if (conv == 0)      { const int h = (npos / 20) % 20; gm = h > 0; gp = h < 19; off = 20; }
        else if (conv == 1) { const int d = npos / 400;       gm = d > 0; gp = d < 19; off = 400; }
        else                { const int w = npos % 20;        gm = w > 0; gp = w < 19; off = 1; }
        const int rm = gm ? npos - off : npos;
        const int rp = gp ? npos + off : npos;

#pragma unroll
        for (int kh = 0; kh < 2; ++kh) {
            const int ko = kh * 32 + q4 * 8;
            half8_t a0 = *(const half8_t*)(xb + (size_t)rm * 64 + ko);
            const half8_t a1 = *(const half8_t*)(xb + (size_t)npos * 64 + ko);
            half8_t a2 = *(const half8_t*)(xb + (size_t)rp * 64 + ko);
            a0 = gm ? a0 : z8;
            a2 = gp ? a2 : z8;
#pragma unroll
            for (int cb = 0; cb < 4; ++cb) {
                acc[mt][cb] = __builtin_amdgcn_mfma_f32_16x16x32_f16(a0, wf[0][kh][cb], acc[mt][cb], 0, 0, 0);
                acc[mt][cb] = __builtin_amdgcn_mfma_f32_16x16x32_f16(a1, wf[1][kh][cb], acc[mt][cb], 0, 0, 0);
                acc[mt][cb] = __builtin_amdgcn_mfma_f32_16x16x32_f16(a2, wf[2][kh][cb], acc[mt][cb], 0, 0, 0);
            }
        }
    }

    if (conv < 2) {
        _Float16* dst = (conv == 0) ? Qt : Kt;
#pragma unroll
        for (int mt = 0; mt < 2; ++mt)
#pragma unroll
            for (int cb = 0; cb < 4; ++cb)
#pragma unroll
                for (int reg = 0; reg < 4; ++reg) {
                    const int n = n0 + mt * 16 + q4 * 4 + reg;
                    dst[((size_t)b * 8000 + n) * 64 + cb * 16 + lm] = (_Float16)acc[mt][cb][reg];
                }
    } else {
#pragma unroll
        for (int mt = 0; mt < 2; ++mt)
#pragma unroll
            for (int cb = 0; cb < 4; ++cb) {
                ushort4_t vvv;
#pragma unroll
                for (int reg = 0; reg < 4; ++reg) vvv[reg] = f2bf(acc[mt][cb][reg]);
                *(ushort4_t*)(Vt + ((size_t)b * 64 + cb * 16 + lm) * 8000 + n0 + mt * 16 + q4 * 4) = vvv;
            }
    }
}

// ---------------------------------------------------------------------------
// Kernel C: flash attention, 32-row waves, SINGLE-buffered 16 KB LDS.
// R14 proved residency is capped at ~2 blocks x 32 KB = 64 KB effective LDS
// pool — halving LDS/block is the occupancy lever. Pipeline per tile:
// barrier -> ds_write regs (prefetched a tile ago, no vmcnt stall) -> issue
// next tile's global loads -> barrier -> compute. S^T register trick, l on
// the MFMA pipe (all-ones A), P packed by truncation (error cancels in O/l).
// ---------------------------------------------------------------------------
__global__ __launch_bounds__(256, 2) void attn_kernel(
    const _Float16* __restrict__ Qt, const _Float16* __restrict__ Kt,
    const unsigned short* __restrict__ Vt,
    _Float16* __restrict__ Oseg, float* __restrict__ Wseg)
{
    __shared__ __align__(16) _Float16       k_lds[4096];  // [n][c-chunks ^ (n&7)]
    __shared__ __align__(16) unsigned short v_lds[4096];  // [c][n-chunks ^ (c&7)]

    const int tid = threadIdx.x;
    const int wv  = tid >> 6;
    const int L   = tid & 63;
    const int q4  = L >> 4;
    const int lm  = L & 15;
    const int qt  = blockIdx.x;          // 0..62, 128 rows per block
    const int b   = blockIdx.y;
    const int sp  = blockIdx.z;
    const int NS  = gridDim.z;
    const int t0  = (125 * sp) / NS;
    const int t1  = (125 * (sp + 1)) / NS;
    const int unit = qt * 4 + wv;        // 32-row unit, valid if < 250

    const _Float16* Qb = Qt + ((size_t)b * 8000 + (size_t)qt * 128 + wv * 32 + lm) * 64 + q4 * 8;
    half8_t bq00 = *(const half8_t*)(Qb);
    half8_t bq01 = *(const half8_t*)(Qb + 32);
    half8_t bq10 = *(const half8_t*)(Qb + 16 * 64);
    half8_t bq11 = *(const half8_t*)(Qb + 16 * 64 + 32);

    f32x4_t o[2][4];
    f32x4_t acc_l[2];
#pragma unroll
    for (int mt = 0; mt < 2; ++mt) {
        acc_l[mt] = (f32x4_t){0.f, 0.f, 0.f, 0.f};
#pragma unroll
        for (int cb = 0; cb < 4; ++cb) o[mt][cb] = (f32x4_t){0.f, 0.f, 0.f, 0.f};
    }
    const short4_t ones4 = {(short)0x3F80, (short)0x3F80, (short)0x3F80, (short)0x3F80};

    const _Float16*       Kg = Kt + (size_t)b * 512000;
    const unsigned short* Vg = Vt + (size_t)b * 512000;
    const int r0  = tid >> 3;   // 0..31
    const int cc0 = tid & 7;
    const int swz_lo = r0 * 64 + ((cc0 ^ (r0 & 7)) * 8);
    const int swz_hi = (r0 + 32) * 64 + ((cc0 ^ (r0 & 7)) * 8);
    const _Float16*       Kr0 = Kg + (size_t)r0 * 64 + cc0 * 8;
    const _Float16*       Kr1 = Kg + (size_t)(r0 + 32) * 64 + cc0 * 8;
    const unsigned short* Vr0 = Vg + (size_t)r0 * 8000 + cc0 * 8;
    const unsigned short* Vr1 = Vg + (size_t)(r0 + 32) * 8000 + cc0 * 8;

    uint4 sk0, sk1, sv0, sv1;   // register-staged next tile

    {
        const int n0 = t0 * 64;
        sk0 = *(const uint4*)(Kr0 + (size_t)n0 * 64);
        sk1 = *(const uint4*)(Kr1 + (size_t)n0 * 64);
        sv0 = *(const uint4*)(Vr0 + n0);
        sv1 = *(const uint4*)(Vr1 + n0);
    }

    for (int kt = t0; kt < t1; ++kt) {
        __syncthreads();   // all waves done READING the buffer (prev tile)
        *(uint4*)(&k_lds[swz_lo]) = sk0;   // regs long arrived: no vmcnt stall
        *(uint4*)(&k_lds[swz_hi]) = sk1;
        *(uint4*)(&v_lds[swz_lo]) = sv0;
        *(uint4*)(&v_lds[swz_hi]) = sv1;
        if (kt + 1 < t1) {
            const int n1 = (kt + 1) * 64;   // issue early, overlaps barrier+compute
            sk0 = *(const uint4*)(Kr0 + (size_t)n1 * 64);
            sk1 = *(const uint4*)(Kr1 + (size_t)n1 * 64);
            sv0 = *(const uint4*)(Vr0 + n1);
            sv1 = *(const uint4*)(Vr1 + n1);
        }
        __syncthreads();   // buffer fully written

        short4_t pfr[2][4];
#pragma unroll
        for (int ns = 0; ns < 4; ++ns) {
            const int n = ns * 16 + lm;
            const _Float16* krow = &k_lds[n * 64];
            const half8_t ak0 = *(const half8_t*)(krow + (((q4    ) ^ (n & 7)) * 8));
            const half8_t ak1 = *(const half8_t*)(krow + (((q4 + 4) ^ (n & 7)) * 8));
#pragma unroll
            for (int mt = 0; mt < 2; ++mt) {
                f32x4_t z = (f32x4_t){0.f, 0.f, 0.f, 0.f};
                z = __builtin_amdgcn_mfma_f32_16x16x32_f16(ak0, mt ? bq10 : bq00, z, 0, 0, 0);
                z = __builtin_amdgcn_mfma_f32_16x16x32_f16(ak1, mt ? bq11 : bq01, z, 0, 0, 0);
                short4_t pk;
#pragma unroll
                for (int reg = 0; reg < 4; ++reg)
                    pk[reg] = (short)f2bf_trunc(exp2f(z[reg]));   // Qt pre-scaled by log2e
                pfr[mt][ns] = pk;
            }
        }

        // l on the MFMA pipe: all-ones A -> every D row = sum_k P[k][m]
#pragma unroll
        for (int mt = 0; mt < 2; ++mt)
#pragma unroll
            for (int ns = 0; ns < 4; ++ns)
                acc_l[mt] = __builtin_amdgcn_mfma_f32_16x16x16bf16_1k(ones4, pfr[mt][ns], acc_l[mt], 0, 0, 0);

#pragma unroll
        for (int cb = 0; cb < 4; ++cb) {
            const int c = cb * 16 + lm;
            const unsigned short* vrow = &v_lds[c * 64];
            f32x4_t a0 = o[0][cb], a1 = o[1][cb];
#pragma unroll
            for (int ns = 0; ns < 4; ++ns) {
                const int cc = ns * 2 + (q4 >> 1);
                const short4_t av = *(const short4_t*)(vrow + ((cc ^ (c & 7)) * 8) + (q4 & 1) * 4);
                a0 = __builtin_amdgcn_mfma_f32_16x16x16bf16_1k(av, pfr[0][ns], a0, 0, 0, 0);
                a1 = __builtin_amdgcn_mfma_f32_16x16x16bf16_1k(av, pfr[1][ns], a1, 0, 0, 0);
            }
            o[0][cb] = a0;
            o[1][cb] = a1;
        }
    }

    if (unit >= 250) return;  // tail qtile (after all barriers)

    float rinv[2], lg[2];
#pragma unroll
    for (int mt = 0; mt < 2; ++mt) {
        const float l = acc_l[mt][0];   // all D rows equal the column sum
        rinv[mt] = 1.0f / l;
        lg[mt]   = __log2f(l);
    }

    const int seg = (b * 250 + unit) * NS + sp;
    _Float16* os = Oseg + (size_t)seg * 2048;
#pragma unroll
    for (int mt = 0; mt < 2; ++mt) {
#pragma unroll
        for (int cb = 0; cb < 4; ++cb) {
            half4_t e;
#pragma unroll
            for (int reg = 0; reg < 4; ++reg) e[reg] = (_Float16)(o[mt][cb][reg] * rinv[mt]);
            *(half4_t*)(os + (mt * 16 + lm) * 64 + cb * 16 + q4 * 4) = e;
        }
    }
    if (q4 == 0) {
#pragma unroll
        for (int mt = 0; mt < 2; ++mt)
            Wseg[(size_t)seg * 32 + mt * 16 + lm] = lg[mt];
    }
}

// ---------------------------------------------------------------------------
// Kernel D: combine NS partials per (b, 32-row unit). NS up to 16.
// ---------------------------------------------------------------------------
__global__ __launch_bounds__(256, 2) void combine_kernel(
    const _Float16* __restrict__ Oseg, const float* __restrict__ Wseg,
    const int* __restrict__ flag, void* __restrict__ outv, int NS)
{
    __shared__ float wls[16 * 32];
    __shared__ float cls[16 * 32];
    const int tid = threadIdx.x;
    const int qt = blockIdx.x, b = blockIdx.y;
    const int base = (b * 250 + qt) * NS;

    for (int i = tid; i < NS * 32; i += 256) wls[i] = Wseg[(size_t)base * 32 + i];
    __syncthreads();
    if (tid < 32) {
        const int r = tid;
        float wm = wls[r];
        for (int s2 = 1; s2 < NS; ++s2) wm = fmaxf(wm, wls[s2 * 32 + r]);
        float cs = 0.f;
        for (int s2 = 0; s2 < NS; ++s2) {
            float cc = exp2f(wls[s2 * 32 + r] - wm);
            cls[s2 * 32 + r] = cc;
            cs += cc;
        }
        const float inv = 1.f / cs;
        for (int s2 = 0; s2 < NS; ++s2) cls[s2 * 32 + r] *= inv;
    }
    __syncthreads();

    const int c = tid & 63, rg = tid >> 6;
    float acc[8];
#pragma unroll
    for (int i = 0; i < 8; ++i) acc[i] = 0.f;
    for (int s2 = 0; s2 < NS; ++s2) {
        const _Float16* src = Oseg + ((size_t)(base + s2)) * 2048 + rg * 8 * 64 + c;
        const float* cf = &cls[s2 * 32 + rg * 8];
#pragma unroll
        for (int i = 0; i < 8; ++i) acc[i] += (float)src[i * 64] * cf[i];
    }

    const size_t ob = ((size_t)b * 64 + c) * 8000 + qt * 32 + rg * 8;
    if (*flag) {
        uint4 u0;
        u0.x = f2bf(acc[0]) | ((unsigned)f2bf(acc[1]) << 16);
        u0.y = f2bf(acc[2]) | ((unsigned)f2bf(acc[3]) << 16);
        u0.z = f2bf(acc[4]) | ((unsigned)f2bf(acc[5]) << 16);
        u0.w = f2bf(acc[6]) | ((unsigned)f2bf(acc[7]) << 16);
        *(uint4*)((unsigned short*)outv + ob) = u0;
    } else {
        float* o32 = (float*)outv + ob;
        *(f32x4_t*)(o32)     = (f32x4_t){acc[0], acc[1], acc[2], acc[3]};
        *(f32x4_t*)(o32 + 4) = (f32x4_t){acc[4], acc[5], acc[6], acc[7]};
    }
}

// ---------------------------------------------------------------------------
// Workspace layout (bytes):
//   [0,4)                  flag
//   [2304,3072)            bb   : 3x64 fp32 biases (Q pre-scaled by log2e)
//   [3072,76800)           w2   : [3][3][64][64] fp16 GEMM weights (Q scaled)
//   [76800,2124800)        Qt   : [2][8000][64] fp16 (pre-scaled by log2e)
//   [2124800,4172800)      Kt   : [2][8000][64] fp16
//   [4172800,6220800)      Vt   : [2][64][8000] bf16
//   [6220800, ...)         union { xT (dead before attn)
//                                 | Oseg [2*250*NS][32][64] fp16 + Wseg fp32 }
// NS=16 needs 40,012,800 B; NS=8 needs 23,116,800 B (proven); else NS=1.
// ---------------------------------------------------------------------------
extern "C" void kernel_launch(void* const* d_in, const int* in_sizes, int n_in,
                              void* d_out, int out_size, void* d_ws, size_t ws_size,
                              hipStream_t stream)
{
    (void)in_sizes; (void)n_in; (void)out_size;
    const void* x  = d_in[0];
    const void* qw = d_in[1];
    const void* qb = d_in[2];
    const void* kw = d_in[3];
    const void* kb = d_in[4];
    const void* vw = d_in[5];
    const void* vb = d_in[6];

    char* ws = (char*)d_ws;
    int*            flag = (int*)ws;
    float*          bb   = (float*)(ws + 2304);
    _Float16*       w2   = (_Float16*)(ws + 3072);
    _Float16*       Qt   = (_Float16*)(ws + 76800);
    _Float16*       Kt   = (_Float16*)(ws + 2124800);
    unsigned short* Vt   = (unsigned short*)(ws + 4172800);
    _Float16*       xT   = (_Float16*)(ws + 6220800);

    const size_t need16 = 6220800 + (size_t)2 * 250 * 16 * 2048 * 2 + (size_t)2 * 250 * 16 * 32 * 4;
    const size_t need8  = 6220800 + (size_t)2 * 250 * 8  * 2048 * 2 + (size_t)2 * 250 * 8  * 32 * 4;
    const int NS = (ws_size >= need16) ? 16 : (ws_size >= need8) ? 8 : 1;
    _Float16* Oseg = (_Float16*)(ws + 6220800);
    float*    Wseg = (float*)(ws + 6220800 + (size_t)2 * 250 * NS * 2048 * 2);

    prep_kernel<<<dim3(394), 256, 0, stream>>>(x, qw, kw, vw, qb, kb, vb, flag, w2, bb, xT);
    convg_kernel<<<dim3(375), 256, 0, stream>>>(xT, w2, bb, Qt, Kt, Vt);
    attn_kernel<<<dim3(63, 2, NS), 256, 0, stream>>>(Qt, Kt, Vt, Oseg, Wseg);
    combine_kernel<<<dim3(250, 2), 256, 0, stream>>>(Oseg, Wseg, flag, d_out, NS);
}

// Round 16
// 142.501 us; speedup vs baseline: 1.1055x; 1.1055x over previous
//
#include <hip/hip_runtime.h>
#include <cstdint>
#include <cstddef>

typedef _Float16 half4_t  __attribute__((ext_vector_type(4)));
typedef _Float16 half8_t  __attribute__((ext_vector_type(8)));
typedef short    short4_t __attribute__((ext_vector_type(4)));
typedef unsigned short ushort4_t __attribute__((ext_vector_type(4)));
typedef float    f32x4_t  __attribute__((ext_vector_type(4)));

#define LOG2E 1.44269504088896340736f

__device__ __forceinline__ float bf2f(unsigned short u) {
    union { unsigned int u; float f; } x;
    x.u = ((unsigned int)u) << 16;
    return x.f;
}
__device__ __forceinline__ unsigned short f2bf(float f) {  // RNE
    union { float f; unsigned int u; } x;
    x.f = f;
    unsigned int r = (x.u + 0x7FFFu + ((x.u >> 16) & 1u)) >> 16;
    return (unsigned short)r;
}
__device__ __forceinline__ unsigned short f2bf_trunc(float f) {  // truncate (positive)
    union { float f; unsigned int u; } x;
    x.f = f;
    return (unsigned short)(x.u >> 16);
}

// ---------------------------------------------------------------------------
// Kernel A: prep + xt fused (unchanged from R12).
// ---------------------------------------------------------------------------
__global__ __launch_bounds__(256) void prep_kernel(
    const void* __restrict__ x,
    const void* __restrict__ qw, const void* __restrict__ kw, const void* __restrict__ vw,
    const void* __restrict__ qb, const void* __restrict__ kb, const void* __restrict__ vb,
    int* __restrict__ flag,
    _Float16* __restrict__ w2, float* __restrict__ bb, _Float16* __restrict__ xT)
{
    __shared__ int scnt;
    __shared__ _Float16 tile[64][66];

    if (threadIdx.x == 0) scnt = 0;
    __syncthreads();
    {
        unsigned int w = ((const unsigned int*)x)[threadIdx.x];
        int e = (w >> 7) & 0xFF;
        int hit = (e == 0) || (e >= 0x68 && e <= 0x88);
        atomicAdd(&scnt, hit);
    }
    __syncthreads();
    const int bf = (scnt >= 128) ? 1 : 0;
    if (blockIdx.x == 0 && threadIdx.x == 0) flag[0] = bf;

    if (blockIdx.x < 144) {
        int idx = blockIdx.x * 256 + threadIdx.x;
        if (idx < 36864) {
            int conv = idx / 12288;
            int r    = idx - conv * 12288;
            int tap  = r >> 12;
            int r2   = r & 4095;
            int co   = r2 >> 6;
            int ci   = r2 & 63;
            const void* w = (conv == 0) ? qw : (conv == 1) ? kw : vw;
            float t;
            if (bf) t = bf2f(((const unsigned short*)w)[co * 192 + ci * 3 + tap]);
            else    t = ((const float*)w)[co * 192 + ci * 3 + tap];
            if (conv == 0) t *= LOG2E;
            w2[idx] = (_Float16)t;
        }
        if (idx < 192) {
            int a = idx >> 6, co = idx & 63;
            const void* s = (a == 0) ? qb : (a == 1) ? kb : vb;
            float t = bf ? bf2f(((const unsigned short*)s)[co]) : ((const float*)s)[co];
            if (a == 0) t *= LOG2E;
            bb[idx] = t;
        }
    } else {
        const int bx   = blockIdx.x - 144;   // 0..249
        const int b    = bx / 125;
        const int n0   = (bx - b * 125) * 64;
        const int lane = threadIdx.x & 63;
        const int wv   = threadIdx.x >> 6;

        if (bf) {
            const unsigned short* xb = (const unsigned short*)x + (size_t)b * 512000 + n0 + lane;
#pragma unroll
            for (int i = 0; i < 16; ++i) {
                const int ci = wv * 16 + i;
                tile[ci][lane] = (_Float16)bf2f(xb[(size_t)ci * 8000]);
            }
        } else {
            const float* xb = (const float*)x + (size_t)b * 512000 + n0 + lane;
#pragma unroll
            for (int i = 0; i < 16; ++i) {
                const int ci = wv * 16 + i;
                tile[ci][lane] = (_Float16)xb[(size_t)ci * 8000];
            }
        }
        __syncthreads();
        _Float16* out = xT + ((size_t)b * 8000 + n0) * 64 + lane;
#pragma unroll
        for (int i = 0; i < 16; ++i) {
            const int r = wv * 16 + i;
            out[(size_t)r * 64] = tile[lane][r];
        }
    }
}

// ---------------------------------------------------------------------------
// Kernel B: the three convs as MFMA GEMMs (unchanged from R10/R12).
// ---------------------------------------------------------------------------
__global__ __launch_bounds__(256, 2) void convg_kernel(
    const _Float16* __restrict__ xT, const _Float16* __restrict__ w2,
    const float* __restrict__ bb,
    _Float16* __restrict__ Qt, _Float16* __restrict__ Kt, unsigned short* __restrict__ Vt)
{
    const int tid = threadIdx.x;
    const int wv  = tid >> 6;
    const int L   = tid & 63;
    const int q4  = L >> 4;
    const int lm  = L & 15;
    const int W    = blockIdx.x * 4 + wv;
    const int conv = W % 3;
    const int u    = W / 3;
    const int b    = u / 250;
    const int n0   = (u - b * 250) * 32;

    half8_t wf[3][2][4];
    const _Float16* wbase = w2 + (size_t)conv * 12288;
#pragma unroll
    for (int tap = 0; tap < 3; ++tap)
#pragma unroll
        for (int kh = 0; kh < 2; ++kh)
#pragma unroll
            for (int cb = 0; cb < 4; ++cb)
                wf[tap][kh][cb] = *(const half8_t*)(
                    wbase + ((size_t)(tap * 64 + cb * 16 + lm)) * 64 + kh * 32 + q4 * 8);

    f32x4_t acc[2][4];
#pragma unroll
    for (int cb = 0; cb < 4; ++cb) {
        const float bi = bb[conv * 64 + cb * 16 + lm];
        const f32x4_t v = (f32x4_t){bi, bi, bi, bi};
        acc[0][cb] = v;
        acc[1][cb] = v;
    }

    const _Float16* xb = xT + (size_t)b * 512000;
    const half8_t z8 = {(_Float16)0, (_Float16)0, (_Float16)0, (_Float16)0,
                        (_Float16)0, (_Float16)0, (_Float16)0, (_Float16)0};

#pragma unroll
    for (int mt = 0; mt < 2; ++mt) {
        const int npos = n0 + mt * 16 + lm;
        int gm, gp, off;
        if (conv == 0)      { const int h = (npos / 20) % 20; gm = h > 0; gp = h < 19; off = 20; }
        else if (conv == 1) { const int d = npos / 400;       gm = d > 0; gp = d < 19; off = 400; }
        else                { const int w = npos % 20;        gm = w > 0; gp = w < 19; off = 1; }
        const int rm = gm ? npos - off : npos;
        const int rp = gp ? npos + off : npos;

#pragma unroll
        for (int kh = 0; kh < 2; ++kh) {
            const int ko = kh * 32 + q4 * 8;
            half8_t a0 = *(const half8_t*)(xb + (size_t)rm * 64 + ko);
            const half8_t a1 = *(const half8_t*)(xb + (size_t)npos * 64 + ko);
            half8_t a2 = *(const half8_t*)(xb + (size_t)rp * 64 + ko);
            a0 = gm ? a0 : z8;
            a2 = gp ? a2 : z8;
#pragma unroll
            for (int cb = 0; cb < 4; ++cb) {
                acc[mt][cb] = __builtin_amdgcn_mfma_f32_16x16x32_f16(a0, wf[0][kh][cb], acc[mt][cb], 0, 0, 0);
                acc[mt][cb] = __builtin_amdgcn_mfma_f32_16x16x32_f16(a1, wf[1][kh][cb], acc[mt][cb], 0, 0, 0);
                acc[mt][cb] = __builtin_amdgcn_mfma_f32_16x16x32_f16(a2, wf[2][kh][cb], acc[mt][cb], 0, 0, 0);
            }
        }
    }

    if (conv < 2) {
        _Float16* dst = (conv == 0) ? Qt : Kt;
#pragma unroll
        for (int mt = 0; mt < 2; ++mt)
#pragma unroll
            for (int cb = 0; cb < 4; ++cb)
#pragma unroll
                for (int reg = 0; reg < 4; ++reg) {
                    const int n = n0 + mt * 16 + q4 * 4 + reg;
                    dst[((size_t)b * 8000 + n) * 64 + cb * 16 + lm] = (_Float16)acc[mt][cb][reg];
                }
    } else {
#pragma unroll
        for (int mt = 0; mt < 2; ++mt)
#pragma unroll
            for (int cb = 0; cb < 4; ++cb) {
                ushort4_t vvv;
#pragma unroll
                for (int reg = 0; reg < 4; ++reg) vvv[reg] = f2bf(acc[mt][cb][reg]);
                *(ushort4_t*)(Vt + ((size_t)b * 64 + cb * 16 + lm) * 8000 + n0 + mt * 16 + q4 * 4) = vvv;
            }
    }
}

// ---------------------------------------------------------------------------
// Kernel C: flash attention, 32-row waves, single-buffered 16 KB LDS,
// __launch_bounds__(256,4): R15 showed 16 KB LDS did NOT raise occupancy ->
// the residency cap is the register budget (arch VGPR 68 + unified AGPRs
// lands just over the 128-reg/8-wave boundary). (256,4) forces <=128 total
// regs -> 16 waves/CU. Pipeline per tile: barrier -> ds_write prefetched
// regs -> issue next tile loads -> barrier -> compute. S^T register trick,
// l on the MFMA pipe (all-ones A), P packed by truncation. Wseg stores
// PLAIN l (scores bounded, all splits share scale — no log weights needed).
// ---------------------------------------------------------------------------
__global__ __launch_bounds__(256, 4) void attn_kernel(
    const _Float16* __restrict__ Qt, const _Float16* __restrict__ Kt,
    const unsigned short* __restrict__ Vt,
    _Float16* __restrict__ Oseg, float* __restrict__ Wseg)
{
    __shared__ __align__(16) _Float16       k_lds[4096];  // [n][c-chunks ^ (n&7)]
    __shared__ __align__(16) unsigned short v_lds[4096];  // [c][n-chunks ^ (c&7)]

    const int tid = threadIdx.x;
    const int wv  = tid >> 6;
    const int L   = tid & 63;
    const int q4  = L >> 4;
    const int lm  = L & 15;
    const int qt  = blockIdx.x;          // 0..62, 128 rows per block
    const int b   = blockIdx.y;
    const int sp  = blockIdx.z;
    const int NS  = gridDim.z;
    const int t0  = (125 * sp) / NS;
    const int t1  = (125 * (sp + 1)) / NS;
    const int unit = qt * 4 + wv;        // 32-row unit, valid if < 250

    const _Float16* Qb = Qt + ((size_t)b * 8000 + (size_t)qt * 128 + wv * 32 + lm) * 64 + q4 * 8;
    half8_t bq00 = *(const half8_t*)(Qb);
    half8_t bq01 = *(const half8_t*)(Qb + 32);
    half8_t bq10 = *(const half8_t*)(Qb + 16 * 64);
    half8_t bq11 = *(const half8_t*)(Qb + 16 * 64 + 32);

    f32x4_t o[2][4];
    f32x4_t acc_l[2];
#pragma unroll
    for (int mt = 0; mt < 2; ++mt) {
        acc_l[mt] = (f32x4_t){0.f, 0.f, 0.f, 0.f};
#pragma unroll
        for (int cb = 0; cb < 4; ++cb) o[mt][cb] = (f32x4_t){0.f, 0.f, 0.f, 0.f};
    }
    const short4_t ones4 = {(short)0x3F80, (short)0x3F80, (short)0x3F80, (short)0x3F80};

    const _Float16*       Kg = Kt + (size_t)b * 512000;
    const unsigned short* Vg = Vt + (size_t)b * 512000;
    const int r0  = tid >> 3;   // 0..31
    const int cc0 = tid & 7;
    const int swz_lo = r0 * 64 + ((cc0 ^ (r0 & 7)) * 8);
    const int swz_hi = (r0 + 32) * 64 + ((cc0 ^ (r0 & 7)) * 8);
    const _Float16*       Kr0 = Kg + (size_t)r0 * 64 + cc0 * 8;
    const _Float16*       Kr1 = Kg + (size_t)(r0 + 32) * 64 + cc0 * 8;
    const unsigned short* Vr0 = Vg + (size_t)r0 * 8000 + cc0 * 8;
    const unsigned short* Vr1 = Vg + (size_t)(r0 + 32) * 8000 + cc0 * 8;

    uint4 sk0, sk1, sv0, sv1;   // register-staged next tile

    {
        const int n0 = t0 * 64;
        sk0 = *(const uint4*)(Kr0 + (size_t)n0 * 64);
        sk1 = *(const uint4*)(Kr1 + (size_t)n0 * 64);
        sv0 = *(const uint4*)(Vr0 + n0);
        sv1 = *(const uint4*)(Vr1 + n0);
    }

    for (int kt = t0; kt < t1; ++kt) {
        __syncthreads();   // all waves done READING the buffer (prev tile)
        *(uint4*)(&k_lds[swz_lo]) = sk0;   // regs long arrived: no vmcnt stall
        *(uint4*)(&k_lds[swz_hi]) = sk1;
        *(uint4*)(&v_lds[swz_lo]) = sv0;
        *(uint4*)(&v_lds[swz_hi]) = sv1;
        if (kt + 1 < t1) {
            const int n1 = (kt + 1) * 64;   // issue early, overlaps barrier+compute
            sk0 = *(const uint4*)(Kr0 + (size_t)n1 * 64);
            sk1 = *(const uint4*)(Kr1 + (size_t)n1 * 64);
            sv0 = *(const uint4*)(Vr0 + n1);
            sv1 = *(const uint4*)(Vr1 + n1);
        }
        __syncthreads();   // buffer fully written

        short4_t pfr[2][4];
#pragma unroll
        for (int ns = 0; ns < 4; ++ns) {
            const int n = ns * 16 + lm;
            const _Float16* krow = &k_lds[n * 64];
            const half8_t ak0 = *(const half8_t*)(krow + (((q4    ) ^ (n & 7)) * 8));
            const half8_t ak1 = *(const half8_t*)(krow + (((q4 + 4) ^ (n & 7)) * 8));
#pragma unroll
            for (int mt = 0; mt < 2; ++mt) {
                f32x4_t z = (f32x4_t){0.f, 0.f, 0.f, 0.f};
                z = __builtin_amdgcn_mfma_f32_16x16x32_f16(ak0, mt ? bq10 : bq00, z, 0, 0, 0);
                z = __builtin_amdgcn_mfma_f32_16x16x32_f16(ak1, mt ? bq11 : bq01, z, 0, 0, 0);
                short4_t pk;
#pragma unroll
                for (int reg = 0; reg < 4; ++reg)
                    pk[reg] = (short)f2bf_trunc(exp2f(z[reg]));   // Qt pre-scaled by log2e
                pfr[mt][ns] = pk;
            }
        }

        // l on the MFMA pipe: all-ones A -> every D row = sum_k P[k][m]
#pragma unroll
        for (int mt = 0; mt < 2; ++mt)
#pragma unroll
            for (int ns = 0; ns < 4; ++ns)
                acc_l[mt] = __builtin_amdgcn_mfma_f32_16x16x16bf16_1k(ones4, pfr[mt][ns], acc_l[mt], 0, 0, 0);

#pragma unroll
        for (int cb = 0; cb < 4; ++cb) {
            const int c = cb * 16 + lm;
            const unsigned short* vrow = &v_lds[c * 64];
            f32x4_t a0 = o[0][cb], a1 = o[1][cb];
#pragma unroll
            for (int ns = 0; ns < 4; ++ns) {
                const int cc = ns * 2 + (q4 >> 1);
                const short4_t av = *(const short4_t*)(vrow + ((cc ^ (c & 7)) * 8) + (q4 & 1) * 4);
                a0 = __builtin_amdgcn_mfma_f32_16x16x16bf16_1k(av, pfr[0][ns], a0, 0, 0, 0);
                a1 = __builtin_amdgcn_mfma_f32_16x16x16bf16_1k(av, pfr[1][ns], a1, 0, 0, 0);
            }
            o[0][cb] = a0;
            o[1][cb] = a1;
        }
    }

    if (unit >= 250) return;  // tail qtile (after all barriers)

    float rinv[2], lv[2];
#pragma unroll
    for (int mt = 0; mt < 2; ++mt) {
        const float l = acc_l[mt][0];   // all D rows equal the column sum
        rinv[mt] = 1.0f / l;
        lv[mt]   = l;
    }

    const int seg = (b * 250 + unit) * NS + sp;
    _Float16* os = Oseg + (size_t)seg * 2048;
#pragma unroll
    for (int mt = 0; mt < 2; ++mt) {
#pragma unroll
        for (int cb = 0; cb < 4; ++cb) {
            half4_t e;
#pragma unroll
            for (int reg = 0; reg < 4; ++reg) e[reg] = (_Float16)(o[mt][cb][reg] * rinv[mt]);
            *(half4_t*)(os + (mt * 16 + lm) * 64 + cb * 16 + q4 * 4) = e;
        }
    }
    if (q4 == 0) {
#pragma unroll
        for (int mt = 0; mt < 2; ++mt)
            Wseg[(size_t)seg * 32 + mt * 16 + lm] = lv[mt];
    }
}

// ---------------------------------------------------------------------------
// Kernel D: combine NS partials per (b, 32-row unit). Plain-l weights:
// w_s = l_s / sum_s l_s (all splits share the no-max exp2 scale).
// ---------------------------------------------------------------------------
__global__ __launch_bounds__(256, 2) void combine_kernel(
    const _Float16* __restrict__ Oseg, const float* __restrict__ Wseg,
    const int* __restrict__ flag, void* __restrict__ outv, int NS)
{
    __shared__ float cls[8 * 32];
    const int tid = threadIdx.x;
    const int qt = blockIdx.x, b = blockIdx.y;
    const int base = (b * 250 + qt) * NS;

    for (int i = tid; i < NS * 32; i += 256) cls[i] = Wseg[(size_t)base * 32 + i];
    __syncthreads();
    if (tid < 32) {
        const int r = tid;
        float cs = 0.f;
        for (int s2 = 0; s2 < NS; ++s2) cs += cls[s2 * 32 + r];
        const float inv = 1.f / cs;
        for (int s2 = 0; s2 < NS; ++s2) cls[s2 * 32 + r] *= inv;
    }
    __syncthreads();

    const int c = tid & 63, rg = tid >> 6;
    float acc[8];
#pragma unroll
    for (int i = 0; i < 8; ++i) acc[i] = 0.f;
    for (int s2 = 0; s2 < NS; ++s2) {
        const _Float16* src = Oseg + ((size_t)(base + s2)) * 2048 + rg * 8 * 64 + c;
        const float* cf = &cls[s2 * 32 + rg * 8];
#pragma unroll
        for (int i = 0; i < 8; ++i) acc[i] += (float)src[i * 64] * cf[i];
    }

    const size_t ob = ((size_t)b * 64 + c) * 8000 + qt * 32 + rg * 8;
    if (*flag) {
        uint4 u0;
        u0.x = f2bf(acc[0]) | ((unsigned)f2bf(acc[1]) << 16);
        u0.y = f2bf(acc[2]) | ((unsigned)f2bf(acc[3]) << 16);
        u0.z = f2bf(acc[4]) | ((unsigned)f2bf(acc[5]) << 16);
        u0.w = f2bf(acc[6]) | ((unsigned)f2bf(acc[7]) << 16);
        *(uint4*)((unsigned short*)outv + ob) = u0;
    } else {
        float* o32 = (float*)outv + ob;
        *(f32x4_t*)(o32)     = (f32x4_t){acc[0], acc[1], acc[2], acc[3]};
        *(f32x4_t*)(o32 + 4) = (f32x4_t){acc[4], acc[5], acc[6], acc[7]};
    }
}

// ---------------------------------------------------------------------------
// Workspace layout (bytes):
//   [0,4)                  flag
//   [2304,3072)            bb   : 3x64 fp32 biases (Q pre-scaled by log2e)
//   [3072,76800)           w2   : [3][3][64][64] fp16 GEMM weights (Q scaled)
//   [76800,2124800)        Qt   : [2][8000][64] fp16 (pre-scaled by log2e)
//   [2124800,4172800)      Kt   : [2][8000][64] fp16
//   [4172800,6220800)      Vt   : [2][64][8000] bf16
//   [6220800, ...)         union { xT (dead before attn)
//                                 | Oseg [2*250*NS][32][64] fp16 + Wseg fp32 }
// NS=8 needs 23,116,800 B (proven); else NS=1.
// ---------------------------------------------------------------------------
extern "C" void kernel_launch(void* const* d_in, const int* in_sizes, int n_in,
                              void* d_out, int out_size, void* d_ws, size_t ws_size,
                              hipStream_t stream)
{
    (void)in_sizes; (void)n_in; (void)out_size;
    const void* x  = d_in[0];
    const void* qw = d_in[1];
    const void* qb = d_in[2];
    const void* kw = d_in[3];
    const void* kb = d_in[4];
    const void* vw = d_in[5];
    const void* vb = d_in[6];

    char* ws = (char*)d_ws;
    int*            flag = (int*)ws;
    float*          bb   = (float*)(ws + 2304);
    _Float16*       w2   = (_Float16*)(ws + 3072);
    _Float16*       Qt   = (_Float16*)(ws + 76800);
    _Float16*       Kt   = (_Float16*)(ws + 2124800);
    unsigned short* Vt   = (unsigned short*)(ws + 4172800);
    _Float16*       xT   = (_Float16*)(ws + 6220800);

    const size_t need8 = 6220800 + (size_t)2 * 250 * 8 * 2048 * 2 + (size_t)2 * 250 * 8 * 32 * 4;
    const int NS = (ws_size >= need8) ? 8 : 1;
    _Float16* Oseg = (_Float16*)(ws + 6220800);
    float*    Wseg = (float*)(ws + 6220800 + (size_t)2 * 250 * NS * 2048 * 2);

    prep_kernel<<<dim3(394), 256, 0, stream>>>(x, qw, kw, vw, qb, kb, vb, flag, w2, bb, xT);
    convg_kernel<<<dim3(375), 256, 0, stream>>>(xT, w2, bb, Qt, Kt, Vt);
    attn_kernel<<<dim3(63, 2, NS), 256, 0, stream>>>(Qt, Kt, Vt, Oseg, Wseg);
    combine_kernel<<<dim3(250, 2), 256, 0, stream>>>(Oseg, Wseg, flag, d_out, NS);
}